// Round 1
// baseline (354.697 us; speedup 1.0000x reference)
//
#include <hip/hip_runtime.h>
#include <math.h>

// AdaptiveSelection on MI355X (gfx950)
// Inputs (fp32): cluster_features (8,4096,1024), key_feats (8,1,1024),
//                q_w (128,1024), q_b (128), v_w (1024,1024), v_b (1024)
// Outputs (fp32, concat): selected (1024,1024) then fus (8,1024)
//
// Algebra:
//   logit_i = f_i . w_c  where w_c = q_w^T (q_w key_c + q_b) / sqrt(128)  (+const, dropped)
//   A = softmax(logit); topk-128 by A == topk by logit (monotone)
//   fusion = v_w @ (A^T feats) + v_b     (sum A = 1)

#define DIM   1024
#define NC    8
#define NPER  4096
#define QD    128
#define TOPK  128
#define K1B   32      // blocks per cluster in main pass

// ---------------- K0: per-cluster projection vector w_c ----------------
__global__ __launch_bounds__(256) void k0_prep(
    const float* __restrict__ key_feats,  // (8,1024)
    const float* __restrict__ q_w,        // (128,1024)
    const float* __restrict__ q_b,        // (128)
    float* __restrict__ w_all)            // (8,1024)
{
    const int c   = blockIdx.x;
    const int tid = threadIdx.x;          // 256
    __shared__ float qk[QD];
    __shared__ float part[256];

    // step 1: qk[k] = dot(q_w[k], key_c) + q_b[k]; two threads per k
    {
        const int k    = tid >> 1;
        const int half = tid & 1;
        const float4* qr4 = (const float4*)(q_w + (size_t)k * DIM + half * 512);
        const float4* kf4 = (const float4*)(key_feats + (size_t)c * DIM + half * 512);
        float s = 0.f;
        #pragma unroll 4
        for (int j = 0; j < 128; ++j) {
            float4 a = qr4[j], b = kf4[j];
            s += a.x*b.x + a.y*b.y + a.z*b.z + a.w*b.w;
        }
        part[tid] = s;
    }
    __syncthreads();
    if (tid < QD) qk[tid] = part[2*tid] + part[2*tid+1] + q_b[tid];
    __syncthreads();

    // step 2: w[j] = (sum_k q_w[k][j] * qk[k]) / sqrt(128); coalesced over j
    const float scale = 1.0f / sqrtf((float)QD);
    for (int j = tid; j < DIM; j += 256) {
        float s = 0.f;
        #pragma unroll 8
        for (int k = 0; k < QD; ++k)
            s += q_w[(size_t)k * DIM + j] * qk[k];
        w_all[c * DIM + j] = s * scale;
    }
}

// ---------------- K1: fused logits + online-softmax weighted row sum ----------------
// grid (K1B, NC), block 256 = 4 waves; one wave per row, 32 rows/wave.
__global__ __launch_bounds__(256) void k1_main(
    const float* __restrict__ feats,   // (8,4096,1024)
    const float* __restrict__ w_all,   // (8,1024)
    float* __restrict__ logits,        // (8,4096)
    float* __restrict__ pacc,          // (8*K1B,1024)
    float* __restrict__ pm,            // (8*K1B)
    float* __restrict__ pz)            // (8*K1B)
{
    const int c    = blockIdx.y;
    const int blk  = blockIdx.x;       // 0..K1B-1
    const int tid  = threadIdx.x;
    const int lane = tid & 63;
    const int wave = tid >> 6;         // 0..3

    // per-lane slice of w_c: element j = 4*(lane + 64q) + comp
    const float4* w4 = (const float4*)(w_all + c * DIM);
    float4 wv[4];
    #pragma unroll
    for (int q = 0; q < 4; ++q) wv[q] = w4[lane + 64*q];

    float4 acc[4];
    #pragma unroll
    for (int q = 0; q < 4; ++q) acc[q] = make_float4(0.f, 0.f, 0.f, 0.f);
    float m = -INFINITY, Z = 0.f;

    const int wslot = blk * 4 + wave;  // 0..127 within cluster
    const float* fc = feats + (size_t)c * NPER * DIM;

    for (int it = 0; it < NPER / 128; ++it) {
        const int r = wslot + 128 * it;
        const float4* f4 = (const float4*)(fc + (size_t)r * DIM);
        float4 f[4];
        #pragma unroll
        for (int q = 0; q < 4; ++q) f[q] = f4[lane + 64*q];

        float p = 0.f;
        #pragma unroll
        for (int q = 0; q < 4; ++q)
            p += f[q].x*wv[q].x + f[q].y*wv[q].y + f[q].z*wv[q].z + f[q].w*wv[q].w;
        #pragma unroll
        for (int off = 32; off > 0; off >>= 1)
            p += __shfl_xor(p, off, 64);
        if (lane == 0) logits[c * NPER + r] = p;

        const float mn   = fmaxf(m, p);
        const float sOld = __expf(m - mn);   // m=-inf first iter -> 0
        const float t    = __expf(p - mn);
        Z = Z * sOld + t;
        #pragma unroll
        for (int q = 0; q < 4; ++q) {
            acc[q].x = acc[q].x * sOld + t * f[q].x;
            acc[q].y = acc[q].y * sOld + t * f[q].y;
            acc[q].z = acc[q].z * sOld + t * f[q].z;
            acc[q].w = acc[q].w * sOld + t * f[q].w;
        }
        m = mn;
    }

    // block-level combine of the 4 wave partials
    __shared__ float sm[4], sz[4];
    __shared__ float sacc[4][DIM];     // 16 KB
    if (lane == 0) { sm[wave] = m; sz[wave] = Z; }
    #pragma unroll
    for (int q = 0; q < 4; ++q)
        ((float4*)sacc[wave])[lane + 64*q] = acc[q];
    __syncthreads();

    const float mb = fmaxf(fmaxf(sm[0], sm[1]), fmaxf(sm[2], sm[3]));
    const float e0 = __expf(sm[0] - mb), e1 = __expf(sm[1] - mb);
    const float e2 = __expf(sm[2] - mb), e3 = __expf(sm[3] - mb);
    float4 a0 = ((float4*)sacc[0])[tid];
    float4 a1 = ((float4*)sacc[1])[tid];
    float4 a2 = ((float4*)sacc[2])[tid];
    float4 a3 = ((float4*)sacc[3])[tid];
    float4 o;
    o.x = a0.x*e0 + a1.x*e1 + a2.x*e2 + a3.x*e3;
    o.y = a0.y*e0 + a1.y*e1 + a2.y*e2 + a3.y*e3;
    o.z = a0.z*e0 + a1.z*e1 + a2.z*e2 + a3.z*e3;
    o.w = a0.w*e0 + a1.w*e1 + a2.w*e2 + a3.w*e3;
    ((float4*)(pacc + (size_t)(c * K1B + blk) * DIM))[tid] = o;
    if (tid == 0) {
        pm[c * K1B + blk] = mb;
        pz[c * K1B + blk] = sz[0]*e0 + sz[1]*e1 + sz[2]*e2 + sz[3]*e3;
    }
}

// ---------------- K2: combine block partials -> g_c = (A^T feats) ----------------
__global__ __launch_bounds__(256) void k2_combine(
    const float* __restrict__ pacc, const float* __restrict__ pm,
    const float* __restrict__ pz, float* __restrict__ g)  // (8,1024)
{
    const int c = blockIdx.x, tid = threadIdx.x;
    float mc = -INFINITY;
    for (int b = 0; b < K1B; ++b) mc = fmaxf(mc, pm[c*K1B + b]);
    float zc = 0.f;
    for (int b = 0; b < K1B; ++b) zc += pz[c*K1B + b] * __expf(pm[c*K1B + b] - mc);
    float4 s = make_float4(0.f, 0.f, 0.f, 0.f);
    for (int b = 0; b < K1B; ++b) {
        const float e = __expf(pm[c*K1B + b] - mc);
        float4 a = ((const float4*)(pacc + (size_t)(c*K1B + b) * DIM))[tid];
        s.x += e*a.x; s.y += e*a.y; s.z += e*a.z; s.w += e*a.w;
    }
    const float inv = 1.0f / zc;
    s.x *= inv; s.y *= inv; s.z *= inv; s.w *= inv;
    ((float4*)(g + c * DIM))[tid] = s;
}

// ---------------- K3: exact top-k placement via rank counting ----------------
// Strict total order: (value desc, index asc) == jax.lax.top_k stable semantics.
__global__ __launch_bounds__(128) void k3_rank(
    const float* __restrict__ logits, int* __restrict__ sel)  // sel (8,128)
{
    const int c = blockIdx.y;
    const int i = blockIdx.x * 128 + threadIdx.x;
    __shared__ float l[NPER];          // 16 KB
    const float4* g4 = (const float4*)(logits + c * NPER);
    float4* l4 = (float4*)l;
    for (int t = threadIdx.x; t < NPER/4; t += 128) l4[t] = g4[t];
    __syncthreads();

    const float li = l[i];
    int r = 0;
    for (int j4 = 0; j4 < NPER/4; ++j4) {
        float4 v = l4[j4];
        const int j = 4 * j4;
        r += (v.x > li) || (v.x == li && (j+0) < i);
        r += (v.y > li) || (v.y == li && (j+1) < i);
        r += (v.z > li) || (v.z == li && (j+2) < i);
        r += (v.w > li) || (v.w == li && (j+3) < i);
    }
    if (r < TOPK) sel[c * TOPK + r] = i;
}

// ---------------- K4: gather selected rows (exact fp32 copies) ----------------
__global__ __launch_bounds__(256) void k4_gather(
    const float* __restrict__ feats, const int* __restrict__ sel,
    float* __restrict__ out_sel)       // (1024,1024)
{
    const int b = blockIdx.x;          // 0..1023
    const int c = b >> 7;
    const int i = sel[b];
    const float4* src = (const float4*)(feats + ((size_t)c * NPER + i) * DIM);
    float4* dst = (float4*)(out_sel + (size_t)b * DIM);
    dst[threadIdx.x] = src[threadIdx.x];
}

// ---------------- K5: fus_c = v_w @ g_c + v_b ----------------
// grid (64, NC), block 256 = 4 waves; wave computes 4 outputs.
__global__ __launch_bounds__(256) void k5_fusion(
    const float* __restrict__ v_w,     // (1024,1024)
    const float* __restrict__ v_b,     // (1024)
    const float* __restrict__ g,       // (8,1024)
    float* __restrict__ fus)           // (8,1024)
{
    const int c    = blockIdx.y;
    const int tid  = threadIdx.x;
    const int lane = tid & 63;
    const int wave = tid >> 6;

    const float4* g4 = (const float4*)(g + c * DIM);
    float4 gv[4];
    #pragma unroll
    for (int q = 0; q < 4; ++q) gv[q] = g4[lane + 64*q];

    const int obase = blockIdx.x * 16 + wave * 4;
    for (int q = 0; q < 4; ++q) {
        const int o = obase + q;
        const float4* vr = (const float4*)(v_w + (size_t)o * DIM);
        float p = 0.f;
        #pragma unroll
        for (int u = 0; u < 4; ++u) {
            float4 a = vr[lane + 64*u];
            p += a.x*gv[u].x + a.y*gv[u].y + a.z*gv[u].z + a.w*gv[u].w;
        }
        #pragma unroll
        for (int off = 32; off > 0; off >>= 1)
            p += __shfl_xor(p, off, 64);
        if (lane == 0) fus[c * DIM + o] = p + v_b[o];
    }
}

extern "C" void kernel_launch(void* const* d_in, const int* in_sizes, int n_in,
                              void* d_out, int out_size, void* d_ws, size_t ws_size,
                              hipStream_t stream) {
    const float* feats     = (const float*)d_in[0];
    const float* key_feats = (const float*)d_in[1];
    const float* q_w       = (const float*)d_in[2];
    const float* q_b       = (const float*)d_in[3];
    const float* v_w       = (const float*)d_in[4];
    const float* v_b       = (const float*)d_in[5];
    float* out      = (float*)d_out;
    float* out_sel  = out;                       // 1024*1024
    float* out_fus  = out + (size_t)1024 * 1024; // 8*1024

    // workspace layout (floats)
    float* ws     = (float*)d_ws;
    float* w_all  = ws;                           // 8*1024
    float* logits = w_all  + NC * DIM;            // 8*4096
    float* pacc   = logits + NC * NPER;           // 8*K1B*1024
    float* pm     = pacc   + (size_t)NC * K1B * DIM;  // 256
    float* pz     = pm     + NC * K1B;            // 256
    float* g      = pz     + NC * K1B;            // 8*1024
    int*   sel    = (int*)(g + NC * DIM);         // 1024 ints

    k0_prep   <<<dim3(NC),        256, 0, stream>>>(key_feats, q_w, q_b, w_all);
    k1_main   <<<dim3(K1B, NC),   256, 0, stream>>>(feats, w_all, logits, pacc, pm, pz);
    k2_combine<<<dim3(NC),        256, 0, stream>>>(pacc, pm, pz, g);
    k3_rank   <<<dim3(NPER/128, NC), 128, 0, stream>>>(logits, sel);
    k4_gather <<<dim3(NC * TOPK), 256, 0, stream>>>(feats, sel, out_sel);
    k5_fusion <<<dim3(64, NC),    256, 0, stream>>>(v_w, v_b, g, out_fus);
}

// Round 2
// 271.498 us; speedup vs baseline: 1.3064x; 1.3064x over previous
//
#include <hip/hip_runtime.h>
#include <math.h>

// AdaptiveSelection on MI355X (gfx950)
// Inputs (fp32): cluster_features (8,4096,1024), key_feats (8,1,1024),
//                q_w (128,1024), q_b (128), v_w (1024,1024), v_b (1024)
// Outputs (fp32, concat): selected (1024,1024) then fus (8,1024)
//
// Algebra:
//   logit_i = f_i . w_c where w_c = q_w^T (q_w key_c + q_b)/sqrt(128) (+const, dropped)
//   topk-128 by logit == topk by softmax (monotone)
//   fusion = v_w @ (A^T feats) + v_b     (sum A = 1)
// Ranking: 64-bit sortable key (ordered float bits << 32 | ~index) makes the
// reference's (value desc, index asc) order a single unsigned compare.

#define DIM   1024
#define NC    8
#define NPER  4096
#define QD    128
#define TOPK  128
#define K1B   64      // blocks per cluster in main streaming pass

typedef unsigned long long u64;
typedef __attribute__((ext_vector_type(2))) unsigned long long ull2;

// ---------------- K0a: qk[c][k] = dot(q_w[k], key_c) + q_b[k] ----------------
__global__ __launch_bounds__(256) void k0a_qk(
    const float* __restrict__ key_feats, const float* __restrict__ q_w,
    const float* __restrict__ q_b, float* __restrict__ qk_all) // (8,128)
{
    const int c = blockIdx.x, tid = threadIdx.x;
    __shared__ float part[256];
    const int k = tid >> 1, half = tid & 1;
    const float4* qr4 = (const float4*)(q_w + (size_t)k * DIM + half * 512);
    const float4* kf4 = (const float4*)(key_feats + (size_t)c * DIM + half * 512);
    float s = 0.f;
    #pragma unroll 8
    for (int j = 0; j < 128; ++j) {
        float4 a = qr4[j], b = kf4[j];
        s += a.x*b.x + a.y*b.y + a.z*b.z + a.w*b.w;
    }
    part[tid] = s;
    __syncthreads();
    if (tid < QD) qk_all[c * QD + tid] = part[2*tid] + part[2*tid+1] + q_b[tid];
}

// ---------------- K0b: w_c[j] = sum_k q_w[k][j] qk[k] / sqrt(128) ----------------
__global__ __launch_bounds__(256) void k0b_w(
    const float* __restrict__ q_w, const float* __restrict__ qk_all,
    float* __restrict__ w_all)  // (8,1024)
{
    const int c = blockIdx.x >> 2, jc = blockIdx.x & 3;
    const int tid = threadIdx.x;
    const int j = jc * 256 + tid;
    __shared__ float qs[QD];
    if (tid < QD) qs[tid] = qk_all[c * QD + tid];
    __syncthreads();
    float s = 0.f;
    #pragma unroll 8
    for (int k = 0; k < QD; ++k)
        s += q_w[(size_t)k * DIM + j] * qs[k];
    w_all[c * DIM + j] = s * 0.08838834764831845f; // 1/sqrt(128)
}

// ---------------- K1: fused logits(keys) + online-softmax weighted row sum ----------
// grid (K1B, NC), block 256 = 4 waves; one wave per row; 16 rows/wave; dbuf prefetch.
__global__ __launch_bounds__(256, 2) void k1_main(
    const float* __restrict__ feats, const float* __restrict__ w_all,
    u64* __restrict__ keys,            // (8,4096) sortable keys
    float* __restrict__ pacc,          // (8*K1B,1024)
    float* __restrict__ pm, float* __restrict__ pz)  // (8*K1B)
{
    const int c    = blockIdx.y;
    const int blk  = blockIdx.x;
    const int tid  = threadIdx.x;
    const int lane = tid & 63;
    const int wave = tid >> 6;

    const float4* w4 = (const float4*)(w_all + c * DIM);
    float4 wv[4];
    #pragma unroll
    for (int q = 0; q < 4; ++q) wv[q] = w4[lane + 64*q];

    float4 acc[4];
    #pragma unroll
    for (int q = 0; q < 4; ++q) acc[q] = make_float4(0.f, 0.f, 0.f, 0.f);
    float m = -INFINITY, Z = 0.f;

    const int wslot = blk * 4 + wave;          // 0..255
    const float* fc = feats + (size_t)c * NPER * DIM;

    float4 fA[4], fB[4];
    {
        const float4* f4 = (const float4*)(fc + (size_t)wslot * DIM);
        #pragma unroll
        for (int q = 0; q < 4; ++q) fA[q] = f4[lane + 64*q];
    }

    #define K1_PROCESS(FREG, ROW)                                              \
    do {                                                                       \
        float p = 0.f;                                                         \
        _Pragma("unroll")                                                      \
        for (int q = 0; q < 4; ++q)                                            \
            p += FREG[q].x*wv[q].x + FREG[q].y*wv[q].y +                       \
                 FREG[q].z*wv[q].z + FREG[q].w*wv[q].w;                        \
        _Pragma("unroll")                                                      \
        for (int off = 32; off > 0; off >>= 1) p += __shfl_xor(p, off, 64);    \
        if (lane == 0) {                                                       \
            unsigned int b = __float_as_uint(p);                               \
            unsigned int u = b ^ ((b & 0x80000000u) ? 0xFFFFFFFFu : 0x80000000u); \
            keys[c * NPER + (ROW)] = ((u64)u << 32) | (unsigned int)(~(ROW));  \
        }                                                                      \
        const float mn   = fmaxf(m, p);                                        \
        const float sOld = __expf(m - mn);                                     \
        const float t    = __expf(p - mn);                                     \
        Z = Z * sOld + t;                                                      \
        _Pragma("unroll")                                                      \
        for (int q = 0; q < 4; ++q) {                                          \
            acc[q].x = acc[q].x * sOld + t * FREG[q].x;                        \
            acc[q].y = acc[q].y * sOld + t * FREG[q].y;                        \
            acc[q].z = acc[q].z * sOld + t * FREG[q].z;                        \
            acc[q].w = acc[q].w * sOld + t * FREG[q].w;                        \
        }                                                                      \
        m = mn;                                                                \
    } while (0)

    for (int it = 0; it < 16; it += 2) {
        const int r0 = wslot + 256 * it;
        {   // prefetch row it+1
            const float4* f4 = (const float4*)(fc + (size_t)(r0 + 256) * DIM);
            #pragma unroll
            for (int q = 0; q < 4; ++q) fB[q] = f4[lane + 64*q];
        }
        K1_PROCESS(fA, r0);
        if (it + 2 < 16) {  // prefetch row it+2
            const float4* f4 = (const float4*)(fc + (size_t)(r0 + 512) * DIM);
            #pragma unroll
            for (int q = 0; q < 4; ++q) fA[q] = f4[lane + 64*q];
        }
        K1_PROCESS(fB, r0 + 256);
    }
    #undef K1_PROCESS

    __shared__ float sm[4], sz[4];
    __shared__ float sacc[4][DIM];
    if (lane == 0) { sm[wave] = m; sz[wave] = Z; }
    #pragma unroll
    for (int q = 0; q < 4; ++q)
        ((float4*)sacc[wave])[lane + 64*q] = acc[q];
    __syncthreads();

    const float mb = fmaxf(fmaxf(sm[0], sm[1]), fmaxf(sm[2], sm[3]));
    const float e0 = __expf(sm[0] - mb), e1 = __expf(sm[1] - mb);
    const float e2 = __expf(sm[2] - mb), e3 = __expf(sm[3] - mb);
    float4 a0 = ((float4*)sacc[0])[tid];
    float4 a1 = ((float4*)sacc[1])[tid];
    float4 a2 = ((float4*)sacc[2])[tid];
    float4 a3 = ((float4*)sacc[3])[tid];
    float4 o;
    o.x = a0.x*e0 + a1.x*e1 + a2.x*e2 + a3.x*e3;
    o.y = a0.y*e0 + a1.y*e1 + a2.y*e2 + a3.y*e3;
    o.z = a0.z*e0 + a1.z*e1 + a2.z*e2 + a3.z*e3;
    o.w = a0.w*e0 + a1.w*e1 + a2.w*e2 + a3.w*e3;
    ((float4*)(pacc + (size_t)(c * K1B + blk) * DIM))[tid] = o;
    if (tid == 0) {
        pm[c * K1B + blk] = mb;
        pz[c * K1B + blk] = sz[0]*e0 + sz[1]*e1 + sz[2]*e2 + sz[3]*e3;
    }
}

// ---------------- K2: combine block partials -> g_c = A^T feats ----------------
__global__ __launch_bounds__(256) void k2_combine(
    const float* __restrict__ pacc, const float* __restrict__ pm,
    const float* __restrict__ pz, float* __restrict__ g)  // (8,1024)
{
    const int c = blockIdx.x, tid = threadIdx.x;
    float mc = -INFINITY;
    for (int b = 0; b < K1B; ++b) mc = fmaxf(mc, pm[c*K1B + b]);
    float zc = 0.f;
    for (int b = 0; b < K1B; ++b) zc += pz[c*K1B + b] * __expf(pm[c*K1B + b] - mc);
    float4 s = make_float4(0.f, 0.f, 0.f, 0.f);
    for (int b = 0; b < K1B; ++b) {
        const float e = __expf(pm[c*K1B + b] - mc);
        float4 a = ((const float4*)(pacc + (size_t)(c*K1B + b) * DIM))[tid];
        s.x += e*a.x; s.y += e*a.y; s.z += e*a.z; s.w += e*a.w;
    }
    const float inv = 1.0f / zc;
    s.x *= inv; s.y *= inv; s.z *= inv; s.w *= inv;
    ((float4*)(g + c * DIM))[tid] = s;
}

// ---------------- K3a: partial rank counts, register-blocked ----------------
// grid (4 i-chunks, 8 j-slices, 8 clusters), block 256. R=4 i's/thread.
__global__ __launch_bounds__(256) void k3a_rank(
    const u64* __restrict__ keys, int* __restrict__ part) // part (8 js,8 c,4096)
{
    const int iblk = blockIdx.x, js = blockIdx.y, c = blockIdx.z;
    const int tid = threadIdx.x;
    __shared__ u64 lk[512];
    ((float4*)lk)[tid] = ((const float4*)(keys + c * NPER + js * 512))[tid];

    const int ibase = iblk * 1024;
    u64 ki[4];
    #pragma unroll
    for (int q = 0; q < 4; ++q) ki[q] = keys[c * NPER + ibase + tid + 256*q];
    __syncthreads();

    int cnt0 = 0, cnt1 = 0, cnt2 = 0, cnt3 = 0;
    const ull2* lk2 = (const ull2*)lk;
    #pragma unroll 4
    for (int jt = 0; jt < 256; ++jt) {
        ull2 kj = lk2[jt];              // wave-uniform broadcast, conflict-free
        cnt0 += (kj.x > ki[0]) + (kj.y > ki[0]);
        cnt1 += (kj.x > ki[1]) + (kj.y > ki[1]);
        cnt2 += (kj.x > ki[2]) + (kj.y > ki[2]);
        cnt3 += (kj.x > ki[3]) + (kj.y > ki[3]);
    }
    int* dst = part + ((js * NC + c) << 12) + ibase + tid;
    dst[0]   = cnt0; dst[256] = cnt1; dst[512] = cnt2; dst[768] = cnt3;
}

// ---------------- K3b: sum partial ranks, scatter selected indices ----------------
__global__ __launch_bounds__(256) void k3b_scatter(
    const int* __restrict__ part, int* __restrict__ sel)  // sel (8,128)
{
    const int c = blockIdx.y;
    const int i = blockIdx.x * 256 + threadIdx.x;
    int r = 0;
    #pragma unroll
    for (int js = 0; js < 8; ++js) r += part[((js * NC + c) << 12) + i];
    if (r < TOPK) sel[c * TOPK + r] = i;
}

// ---------------- K4: gather selected rows (exact fp32 copies) ----------------
__global__ __launch_bounds__(256) void k4_gather(
    const float* __restrict__ feats, const int* __restrict__ sel,
    float* __restrict__ out_sel)
{
    const int b = blockIdx.x;          // 0..1023
    const int c = b >> 7;
    const int i = sel[b];
    const float4* src = (const float4*)(feats + ((size_t)c * NPER + i) * DIM);
    float4* dst = (float4*)(out_sel + (size_t)b * DIM);
    dst[threadIdx.x] = src[threadIdx.x];
}

// ---------------- K5: fus_c = v_w @ g_c + v_b ----------------
__global__ __launch_bounds__(256) void k5_fusion(
    const float* __restrict__ v_w, const float* __restrict__ v_b,
    const float* __restrict__ g, float* __restrict__ fus)
{
    const int c    = blockIdx.y;
    const int tid  = threadIdx.x;
    const int lane = tid & 63;
    const int wave = tid >> 6;

    const float4* g4 = (const float4*)(g + c * DIM);
    float4 gv[4];
    #pragma unroll
    for (int q = 0; q < 4; ++q) gv[q] = g4[lane + 64*q];

    const int obase = blockIdx.x * 16 + wave * 4;
    for (int q = 0; q < 4; ++q) {
        const int o = obase + q;
        const float4* vr = (const float4*)(v_w + (size_t)o * DIM);
        float p = 0.f;
        #pragma unroll
        for (int u = 0; u < 4; ++u) {
            float4 a = vr[lane + 64*u];
            p += a.x*gv[u].x + a.y*gv[u].y + a.z*gv[u].z + a.w*gv[u].w;
        }
        #pragma unroll
        for (int off = 32; off > 0; off >>= 1)
            p += __shfl_xor(p, off, 64);
        if (lane == 0) fus[c * DIM + o] = p + v_b[o];
    }
}

extern "C" void kernel_launch(void* const* d_in, const int* in_sizes, int n_in,
                              void* d_out, int out_size, void* d_ws, size_t ws_size,
                              hipStream_t stream) {
    const float* feats     = (const float*)d_in[0];
    const float* key_feats = (const float*)d_in[1];
    const float* q_w       = (const float*)d_in[2];
    const float* q_b       = (const float*)d_in[3];
    const float* v_w       = (const float*)d_in[4];
    const float* v_b       = (const float*)d_in[5];
    float* out      = (float*)d_out;
    float* out_sel  = out;
    float* out_fus  = out + (size_t)1024 * 1024;

    // workspace layout (8B-aligned first)
    u64*   keys   = (u64*)d_ws;                          // 8*4096 u64 = 256KB
    float* pacc   = (float*)(keys + NC * NPER);          // 8*64*1024 f = 2MB
    float* pm     = pacc + (size_t)NC * K1B * DIM;       // 512
    float* pz     = pm + NC * K1B;                       // 512
    float* g      = pz + NC * K1B;                       // 8*1024
    float* qk_all = g + NC * DIM;                        // 8*128
    float* w_all  = qk_all + NC * QD;                    // 8*1024
    int*   part   = (int*)(w_all + NC * DIM);            // 8*8*4096 = 1MB
    int*   sel    = part + 8 * NC * NPER;                // 1024

    k0a_qk     <<<dim3(NC),           256, 0, stream>>>(key_feats, q_w, q_b, qk_all);
    k0b_w      <<<dim3(NC * 4),       256, 0, stream>>>(q_w, qk_all, w_all);
    k1_main    <<<dim3(K1B, NC),      256, 0, stream>>>(feats, w_all, keys, pacc, pm, pz);
    k2_combine <<<dim3(NC),           256, 0, stream>>>(pacc, pm, pz, g);
    k3a_rank   <<<dim3(4, 8, NC),     256, 0, stream>>>(keys, part);
    k3b_scatter<<<dim3(16, NC),       256, 0, stream>>>(part, sel);
    k4_gather  <<<dim3(NC * TOPK),    256, 0, stream>>>(feats, sel, out_sel);
    k5_fusion  <<<dim3(64, NC),       256, 0, stream>>>(v_w, v_b, g, out_fus);
}